// Round 13
// baseline (2367.911 us; speedup 1.0000x reference)
//
#include <hip/hip_runtime.h>
#include <stdint.h>

#define NBATCH 128
#define NT     64
#define OBD    32
#define ACD    8
#define LDIM   128
#define HDIM   256

typedef _Float16 h2 __attribute__((ext_vector_type(2)));
typedef float    f4 __attribute__((ext_vector_type(4)));

#if defined(__has_builtin)
#  if __has_builtin(__builtin_amdgcn_fdot2)
#    define HAVE_FDOT2 1
#  endif
#endif

__device__ __forceinline__ float dot2f(h2 a, h2 b, float c) {
#ifdef HAVE_FDOT2
  return __builtin_amdgcn_fdot2(a, b, c, false);
#else
  return c + (float)a[0] * (float)b[0] + (float)a[1] * (float)b[1];
#endif
}

__device__ __forceinline__ h2 pkh(float a, float b) {
  h2 r; r[0] = (_Float16)a; r[1] = (_Float16)b; return r;
}

__device__ __forceinline__ h2 bch(float x) { return __builtin_bit_cast(h2, x); }
__device__ __forceinline__ float fch(h2 x) { return __builtin_bit_cast(float, x); }

__device__ __forceinline__ float sigmf(float x) { return 1.0f / (1.0f + expf(-x)); }

// ---- prep: Wd1 (f32 row-major) -> d_ws f16 chunk-major for the 2-row
// geometry: main-kernel thread t owns rows {2(t>>2), 2(t>>2)+1}, K-slice
// (t&3)*64..+63. chunk j: row parity j&1, k-subrange (j>>1)*8.
__global__ void prep_w1(const float* __restrict__ Wd1, f4* __restrict__ ws4) {
  int idx = blockIdx.x * blockDim.x + threadIdx.x;   // 0..8191
  int j  = idx >> 9;
  int tt = idx & 511;
  const float* src = Wd1 + (2 * (tt >> 2) + (j & 1)) * HDIM
                         + (tt & 3) * 64 + (j >> 1) * 8;
  f4 c;
  c.x = fch(pkh(src[0], src[1]));
  c.y = fch(pkh(src[2], src[3]));
  c.z = fch(pkh(src[4], src[5]));
  c.w = fch(pkh(src[6], src[7]));
  ws4[j * 512 + tt] = c;
}

// 2-ROWS-PER-THREAD geometry (r12 analysis: 256 act ds_read_b128/CU/feval
// = ~3000 cyc LDS pipe = the wall; VALU only 19% busy). Each thread now
// computes a row PAIR with narrower K-slice -> act reads halve (16 b128
// /thread/feval), dot2 count unchanged, weight traffic unchanged.
//   stage1: pair G1=t>>2 of h1 (256 rows), K-slice K1=t&3 (32 halfs of z)
//   stage2: pair G2=t>>2 of h2 (256 rows), K-slice K2=t&3 (64 halfs of h1)
//   stage3: pair G3=t>>3 of k  (128 rows), K-slice K3=t&7 (32 halfs of h2)
// Act buffers sliced+padded so slice bases land on disjoint banks:
//   s_in16: 4 x 16 dw data, stride 24 -> bases mod32 {0,24,16,8}
//   s_a16 : 4 x 32 dw data, stride 40 -> bases mod32 {0,8,16,24}
//   s_b16 : 8 x 16 dw data, stride 20 -> bases mod32 {0,20,8,28,16,4,24,12}
// Wd0/Wd2 row-pair fragments resident (32 h2 each); Wd1 streamed from d_ws
// (r12 pipeline, <=6 f4 in flight). RK states for both rows in regs; z-pack
// needs no shfl (both rows in-thread).
__global__ __attribute__((amdgpu_waves_per_eu(2, 2))) __launch_bounds__(512)
void ode_rnn_kernel(const float* __restrict__ ob,   const float* __restrict__ acs,
                    const float* __restrict__ times,
                    const float* __restrict__ We0,  const float* __restrict__ be0,
                    const float* __restrict__ We1,  const float* __restrict__ be1,
                    const float* __restrict__ Wd0,  const float* __restrict__ bd0,
                    const float* __restrict__ bd1,
                    const float* __restrict__ Wd2,  const float* __restrict__ bd2,
                    const float* __restrict__ Wo0,  const float* __restrict__ bo0,
                    const float* __restrict__ Wo1,  const float* __restrict__ bo1,
                    const float* __restrict__ Wih,  const float* __restrict__ Whh,
                    const float* __restrict__ bih,  const float* __restrict__ bn,
                    const f4* __restrict__ ws4,
                    float* __restrict__ out)
{
  const int t  = threadIdx.x;
  const int b  = blockIdx.x;
  const int G1 = t >> 2, K1 = t & 3;   // stage1/stage2 row-pair + K-slice
  const int G3 = t >> 3, K3 = t & 7;   // stage3 row-pair + K-slice
  const int p   = t >> 1;              // decode stage-A row (old mapping)
  const int sub = t & 1;

  __shared__ __align__(16) float s_lat[LDIM];
  __shared__ __align__(16) float s_gz[LDIM];
  __shared__ __align__(16) float s_gin[LDIM];
  __shared__ __align__(16) float s_ghn[LDIM];
  __shared__ __align__(16) float s_tmp[HDIM];
  __shared__ __align__(16) float s_obs[OBD];
  __shared__ __align__(16) float s_times[NT];
  __shared__ __align__(16) float s_acs[NT * ACD];
  __shared__ __align__(16) h2    s_in16[96];    // 4 slices, stride 24 dw
  __shared__ __align__(16) h2    s_a16[152];    // 4 slices, stride 40 dw
  __shared__ __align__(16) h2    s_b16[160];    // 8 slices, stride 20 dw

  // ---- resident weights: Wd0/Wd2 row-pair x K-slice (32 h2 each) ----
  h2 w0[32], w2[32];
  {
    const float2* r0 = (const float2*)(Wd0 + (2 * G1) * LDIM + K1 * 32);
    const float2* r1 = (const float2*)(Wd0 + (2 * G1 + 1) * LDIM + K1 * 32);
#pragma unroll
    for (int i = 0; i < 16; ++i) {
      float2 u = r0[i], v = r1[i];
      w0[i] = pkh(u.x, u.y); w0[16 + i] = pkh(v.x, v.y);
    }
  }
  {
    const float2* r0 = (const float2*)(Wd2 + (2 * G3) * HDIM + K3 * 32);
    const float2* r1 = (const float2*)(Wd2 + (2 * G3 + 1) * HDIM + K3 * 32);
#pragma unroll
    for (int i = 0; i < 16; ++i) {
      float2 u = r0[i], v = r1[i];
      w2[i] = pkh(u.x, u.y); w2[16 + i] = pkh(v.x, v.y);
    }
  }
  const f4* wsb = ws4 + t;             // per-thread w1 stream base

  const float bb00 = bd0[2 * G1], bb01 = bd0[2 * G1 + 1];
  const float bb10 = bd1[2 * G1], bb11 = bd1[2 * G1 + 1];
  const float bb20 = bd2[2 * G3], bb21 = bd2[2 * G3 + 1];
  const float rb0  = bo0[p];
  const float gA   = (t < 3 * LDIM) ? bih[t] : 0.0f;
  const float bnr  = (t < LDIM) ? bn[t] : 0.0f;

  float latr0 = 0.0f, latr1 = 0.0f;    // lat[2G3], lat[2G3+1]

  // ---- one Dopri5 substep; entry: s_in16 = packed lat, latr* = lat ----
  auto substep = [&](float hs) {
    float k00 = 0, k10 = 0, k20 = 0, k30 = 0, k40 = 0;
    float k01 = 0, k11 = 0, k21 = 0, k31 = 0, k41 = 0;
#pragma unroll
    for (int s = 0; s < 6; ++s) {
      // w1 prefetch chunks 0-3 (no deps; land by stage 2)
      f4 y0 = wsb[0 * 512], y1 = wsb[1 * 512];
      f4 y2 = wsb[2 * 512], y3 = wsb[3 * 512];
      float a0, a1, b0, b1, v0, v1;
      // ---- stage 1: h1 pair = relu(Wd0 @ z + bd0) ----
      a0 = a1 = b0 = b1 = 0.0f;
      {
        const f4* act = ((const f4*)s_in16) + K1 * 6;
#pragma unroll
        for (int i = 0; i < 4; ++i) {
          f4 q = act[i];
          a0 = dot2f(w0[4*i+0], bch(q.x), a0);
          a1 = dot2f(w0[4*i+1], bch(q.y), a1);
          a0 = dot2f(w0[4*i+2], bch(q.z), a0);
          a1 = dot2f(w0[4*i+3], bch(q.w), a1);
          b0 = dot2f(w0[16+4*i+0], bch(q.x), b0);
          b1 = dot2f(w0[16+4*i+1], bch(q.y), b1);
          b0 = dot2f(w0[16+4*i+2], bch(q.z), b0);
          b1 = dot2f(w0[16+4*i+3], bch(q.w), b1);
        }
      }
      v0 = a0 + a1; v1 = b0 + b1;
      v0 += __shfl_xor(v0, 1); v0 += __shfl_xor(v0, 2);
      v1 += __shfl_xor(v1, 1); v1 += __shfl_xor(v1, 2);
      v0 = fmaxf(v0 + bb00, 0.0f); v1 = fmaxf(v1 + bb01, 0.0f);
      if (K1 == 0) s_a16[(G1 >> 5) * 40 + (G1 & 31)] = pkh(v0, v1);
      __syncthreads();
      // ---- stage 2: h2 pair = relu(Wd1 @ h1 + bd1), streamed weights ----
      a0 = a1 = b0 = b1 = 0.0f;
      {
        const f4* act = ((const f4*)s_a16) + K1 * 10;
        f4 q;
#define SD2(W0V, W1V, J) q = act[J]; \
        a0 = dot2f(bch(W0V.x), bch(q.x), a0); \
        a1 = dot2f(bch(W0V.y), bch(q.y), a1); \
        a0 = dot2f(bch(W0V.z), bch(q.z), a0); \
        a1 = dot2f(bch(W0V.w), bch(q.w), a1); \
        b0 = dot2f(bch(W1V.x), bch(q.x), b0); \
        b1 = dot2f(bch(W1V.y), bch(q.y), b1); \
        b0 = dot2f(bch(W1V.z), bch(q.z), b0); \
        b1 = dot2f(bch(W1V.w), bch(q.w), b1);
        f4 y4 = wsb[4 * 512],  y5 = wsb[5 * 512];
        SD2(y0, y1, 0)
        f4 y6 = wsb[6 * 512],  y7 = wsb[7 * 512];
        SD2(y2, y3, 1)
        f4 y8 = wsb[8 * 512],  y9 = wsb[9 * 512];
        SD2(y4, y5, 2)
        f4 y10 = wsb[10 * 512], y11 = wsb[11 * 512];
        SD2(y6, y7, 3)
        f4 y12 = wsb[12 * 512], y13 = wsb[13 * 512];
        SD2(y8, y9, 4)
        f4 y14 = wsb[14 * 512], y15 = wsb[15 * 512];
        SD2(y10, y11, 5)
        SD2(y12, y13, 6)
        SD2(y14, y15, 7)
#undef SD2
      }
      v0 = a0 + a1; v1 = b0 + b1;
      v0 += __shfl_xor(v0, 1); v0 += __shfl_xor(v0, 2);
      v1 += __shfl_xor(v1, 1); v1 += __shfl_xor(v1, 2);
      v0 = fmaxf(v0 + bb10, 0.0f); v1 = fmaxf(v1 + bb11, 0.0f);
      if (K1 == 0) s_b16[(G1 >> 4) * 20 + (G1 & 15)] = pkh(v0, v1);
      __syncthreads();
      // ---- stage 3: k pair = Wd2 @ h2 + bd2, fused RK tail ----
      a0 = a1 = b0 = b1 = 0.0f;
      {
        const f4* act = ((const f4*)s_b16) + K3 * 5;
#pragma unroll
        for (int i = 0; i < 4; ++i) {
          f4 q = act[i];
          a0 = dot2f(w2[4*i+0], bch(q.x), a0);
          a1 = dot2f(w2[4*i+1], bch(q.y), a1);
          a0 = dot2f(w2[4*i+2], bch(q.z), a0);
          a1 = dot2f(w2[4*i+3], bch(q.w), a1);
          b0 = dot2f(w2[16+4*i+0], bch(q.x), b0);
          b1 = dot2f(w2[16+4*i+1], bch(q.y), b1);
          b0 = dot2f(w2[16+4*i+2], bch(q.z), b0);
          b1 = dot2f(w2[16+4*i+3], bch(q.w), b1);
        }
      }
      v0 = a0 + a1; v1 = b0 + b1;
      v0 += __shfl_xor(v0, 1); v0 += __shfl_xor(v0, 2); v0 += __shfl_xor(v0, 4);
      v1 += __shfl_xor(v1, 1); v1 += __shfl_xor(v1, 2); v1 += __shfl_xor(v1, 4);
      float kv0 = v0 + bb20, kv1 = v1 + bb21;
      float z0, z1;
      if (s == 0) {
        k00 = kv0; k01 = kv1;
        z0 = latr0 + hs * (0.2f * kv0);
        z1 = latr1 + hs * (0.2f * kv1);
      } else if (s == 1) {
        k10 = kv0; k11 = kv1;
        z0 = latr0 + hs * ((3.0f/40.0f)*k00 + (9.0f/40.0f)*kv0);
        z1 = latr1 + hs * ((3.0f/40.0f)*k01 + (9.0f/40.0f)*kv1);
      } else if (s == 2) {
        k20 = kv0; k21 = kv1;
        z0 = latr0 + hs * ((44.0f/45.0f)*k00 - (56.0f/15.0f)*k10 + (32.0f/9.0f)*kv0);
        z1 = latr1 + hs * ((44.0f/45.0f)*k01 - (56.0f/15.0f)*k11 + (32.0f/9.0f)*kv1);
      } else if (s == 3) {
        k30 = kv0; k31 = kv1;
        z0 = latr0 + hs * ((19372.0f/6561.0f)*k00 - (25360.0f/2187.0f)*k10
                         + (64448.0f/6561.0f)*k20 - (212.0f/729.0f)*kv0);
        z1 = latr1 + hs * ((19372.0f/6561.0f)*k01 - (25360.0f/2187.0f)*k11
                         + (64448.0f/6561.0f)*k21 - (212.0f/729.0f)*kv1);
      } else if (s == 4) {
        k40 = kv0; k41 = kv1;
        z0 = latr0 + hs * ((9017.0f/3168.0f)*k00 - (355.0f/33.0f)*k10
                         + (46732.0f/5247.0f)*k20 + (49.0f/176.0f)*k30
                         - (5103.0f/18656.0f)*kv0);
        z1 = latr1 + hs * ((9017.0f/3168.0f)*k01 - (355.0f/33.0f)*k11
                         + (46732.0f/5247.0f)*k21 + (49.0f/176.0f)*k31
                         - (5103.0f/18656.0f)*kv1);
      } else {
        z0 = latr0 + hs * ((35.0f/384.0f)*k00 + (500.0f/1113.0f)*k20
                         + (125.0f/192.0f)*k30 - (2187.0f/6784.0f)*k40
                         + (11.0f/84.0f)*kv0);
        z1 = latr1 + hs * ((35.0f/384.0f)*k01 + (500.0f/1113.0f)*k21
                         + (125.0f/192.0f)*k31 - (2187.0f/6784.0f)*k41
                         + (11.0f/84.0f)*kv1);
        latr0 = z0; latr1 = z1;
      }
      if (K3 == 0) {
        s_in16[(G3 >> 4) * 24 + (G3 & 15)] = pkh(z0, z1);
        if (s == 5) { s_lat[2*G3] = z0; s_lat[2*G3 + 1] = z1; }
      }
      __syncthreads();
    }
  };

  // ---- GRU (fp32; Wih/Whh streamed from L2) ----
  auto gru = [&](int ts) {
    __syncthreads();                 // publish s_lat
    float vi = gA, vh = 0.0f;
    if (t < 3 * LDIM) {
      const float* xa = s_acs + ts * ACD;
      const f4* wiv = (const f4*)(Wih + t * ACD);
      f4 wa = wiv[0], wb = wiv[1];
      vi += wa.x*xa[0] + wa.y*xa[1] + wa.z*xa[2] + wa.w*xa[3]
          + wb.x*xa[4] + wb.y*xa[5] + wb.z*xa[6] + wb.w*xa[7];
      const f4* wh = (const f4*)(Whh + t * LDIM);
      const f4* xl = (const f4*)s_lat;
#pragma unroll
      for (int k2 = 0; k2 < LDIM / 4; ++k2) {
        f4 w = wh[k2], x = xl[k2];
        vh += w.x*x.x + w.y*x.y + w.z*x.z + w.w*x.w;
      }
    }
    if (t >= LDIM && t < 2 * LDIM)          s_gz[t - LDIM] = vi + vh;
    else if (t >= 2 * LDIM && t < 3 * LDIM) { s_gin[t - 2*LDIM] = vi; s_ghn[t - 2*LDIM] = vh; }
    __syncthreads();
    if (t < LDIM) {
      float rg = sigmf(vi + vh);
      float zg = sigmf(s_gz[t]);
      float ng = tanhf(s_gin[t] + rg * (s_ghn[t] + bnr));
      float y  = (1.0f - zg) * ng + zg * s_lat[t];
      s_lat[t] = y;
      float ov = __shfl_xor(y, 1);
      if (!(t & 1)) {
        int g = t >> 1;
        s_in16[(g >> 4) * 24 + (g & 15)] = pkh(y, ov);
      }
    }
  };

  // ---- decoder (old self-consistent mapping); refreshes latr0/latr1 ----
  auto decode = [&](int ts) {
    __syncthreads();                 // publish s_lat (post-GRU)
    { float2 ld = *(const float2*)(s_lat + 2 * G3); latr0 = ld.x; latr1 = ld.y; }
    float acc = 0.0f;
    {
      const f4* wr = (const f4*)(Wo0 + p * LDIM + sub * 64);
      const f4* xl = ((const f4*)s_lat) + sub * 16;
#pragma unroll
      for (int k2 = 0; k2 < 16; ++k2) {
        f4 w = wr[k2], x = xl[k2];
        acc += w.x*x.x + w.y*x.y + w.z*x.z + w.w*x.w;
      }
    }
    acc += __shfl_xor(acc, 1);
    acc = fmaxf(acc + rb0, 0.0f);
    { float ov = __shfl_xor(acc, 2);
      if ((t & 3) == 0) { int i = t >> 2; s_a16[i + ((i >> 6) << 2)] = pkh(acc, ov); } }
    __syncthreads();
    const int o  = t >> 4;
    const int sl = t & 15;
    float v2 = 0.0f;
    {
      const f4* wr = (const f4*)(Wo1 + o * HDIM + sl * 16);
      const h2* xs = s_a16 + sl * 8 + ((sl >> 3) << 2);
#pragma unroll
      for (int i = 0; i < 4; ++i) {
        f4 w = wr[i];
        h2 xa = xs[2*i], xb = xs[2*i+1];
        v2 += w.x*(float)xa[0] + w.y*(float)xa[1]
            + w.z*(float)xb[0] + w.w*(float)xb[1];
      }
    }
    v2 += __shfl_xor(v2, 1);
    v2 += __shfl_xor(v2, 2);
    v2 += __shfl_xor(v2, 4);
    v2 += __shfl_xor(v2, 8);
    if (sl == 0) out[((size_t)b * NT + ts) * OBD + o] = v2 + bo1[o];
    __syncthreads();                 // protect s_a16 before next substep
  };

  // ================= init + encoder =================
  if (t < OBD) s_obs[t] = ob[b * OBD + t];
  if (t < NT)  s_times[t] = times[b * NT + t];
  s_acs[t] = acs[(size_t)b * NT * ACD + t];   // NT*ACD == 512 == blockDim
  __syncthreads();
  if (t < HDIM) {
    float acc = be0[t];
    const float* wr = We0 + t * OBD;
#pragma unroll
    for (int j = 0; j < OBD; ++j) acc += wr[j] * s_obs[j];
    s_tmp[t] = fmaxf(acc, 0.0f);
  }
  __syncthreads();
  {
    const int rr = t >> 2, kk = t & 3;      // encoder: row rr, K-quarter kk
    const f4* wr = (const f4*)(We1 + rr * HDIM + kk * 64);
    const f4* xs = ((const f4*)s_tmp) + kk * 16;
    float acc = 0.0f;
#pragma unroll
    for (int k = 0; k < 16; ++k) {
      f4 w = wr[k], x = xs[k];
      acc += w.x*x.x + w.y*x.y + w.z*x.z + w.w*x.w;
    }
    acc += __shfl_xor(acc, 1);
    acc += __shfl_xor(acc, 2);
    if (kk == 0) s_lat[rr] = acc + be1[rr];
  }

  // ================= time loop =================
  gru(0);
  decode(0);

#pragma unroll 1
  for (int ts = 1; ts < NT; ++ts) {
    float hs = 0.25f * (s_times[ts] - s_times[ts - 1]);
#pragma unroll 1
    for (int su = 0; su < 4; ++su) substep(hs);
    gru(ts);
    decode(ts);
  }
}

extern "C" void kernel_launch(void* const* d_in, const int* in_sizes, int n_in,
                              void* d_out, int out_size, void* d_ws, size_t ws_size,
                              hipStream_t stream) {
  (void)in_sizes; (void)n_in; (void)ws_size; (void)out_size;
  const float* ob    = (const float*)d_in[0];
  const float* acs   = (const float*)d_in[1];
  const float* times = (const float*)d_in[2];
  const float* We0   = (const float*)d_in[3];
  const float* be0   = (const float*)d_in[4];
  const float* We1   = (const float*)d_in[5];
  const float* be1   = (const float*)d_in[6];
  const float* Wd0   = (const float*)d_in[7];
  const float* bd0   = (const float*)d_in[8];
  const float* Wd1   = (const float*)d_in[9];
  const float* bd1   = (const float*)d_in[10];
  const float* Wd2   = (const float*)d_in[11];
  const float* bd2   = (const float*)d_in[12];
  const float* Wo0   = (const float*)d_in[13];
  const float* bo0   = (const float*)d_in[14];
  const float* Wo1   = (const float*)d_in[15];
  const float* bo1   = (const float*)d_in[16];
  const float* Wih   = (const float*)d_in[17];
  const float* Whh   = (const float*)d_in[18];
  const float* bih   = (const float*)d_in[19];
  const float* bn    = (const float*)d_in[20];

  f4* ws4 = (f4*)d_ws;   // 16 chunks x 512 threads x 16 B = 131072 B

  prep_w1<<<dim3(16), dim3(512), 0, stream>>>(Wd1, ws4);
  ode_rnn_kernel<<<dim3(NBATCH), dim3(512), 0, stream>>>(
      ob, acs, times, We0, be0, We1, be1, Wd0, bd0, bd1, Wd2, bd2,
      Wo0, bo0, Wo1, bo1, Wih, Whh, bih, bn, ws4, (float*)d_out);
}